// Round 11
// baseline (73.460 us; speedup 1.0000x reference)
//
#include <hip/hip_runtime.h>

#define F_BINS  257
#define T_STEPS 65536
#define N_ACT   256
#define TM      256           // t-columns per k_gemm block
#define NBLK_G  256           // T_STEPS / TM  (1 block per CU, single pass)
#define NTHR    512           // 8 waves
#define XO_N4   4210688       // total float4 in x_out (257*65536/4)

typedef float f32x4 __attribute__((ext_vector_type(4)));
typedef short s16x8 __attribute__((ext_vector_type(8)));
typedef unsigned u32x4 __attribute__((ext_vector_type(4)));
typedef unsigned long long u64;

// ws layout:
//   [0]      double Sc
//   [8]      double Sb
//   [16384]  unsigned maskp[NBLK_G*8]
//   [65536]  uchar Gfrag[147456]   (B frags, MFMA order: [kk][n][lane][16B])
#define WS_SC    0
#define WS_SB    8
#define WS_MASK  16384
#define WS_GFRAG 65536

__device__ __forceinline__ unsigned short f2bf_rne(float x) {
  unsigned u = __builtin_bit_cast(unsigned, x);
  return (unsigned short)((u + 0x7FFFu + ((u >> 16) & 1u)) >> 16);
}
// bf16(hi)<<16 | bf16(lo) by truncation: one v_perm_b32
__device__ __forceinline__ unsigned pack_bf(float hi, float lo) {
  return __builtin_amdgcn_perm(__builtin_bit_cast(unsigned, hi),
                               __builtin_bit_cast(unsigned, lo), 0x07060302u);
}
// monotonic float->u32 (order-preserving, finite inputs)
__device__ __forceinline__ unsigned mono(float v) {
  unsigned u = __builtin_bit_cast(unsigned, v);
  return u ^ (unsigned)(((int)u >> 31) | (int)0x80000000);
}

// ---------------------------------------------------------------------------
// B fragments in MFMA order:
// Gfrag[((kk*16+n)*64+lane)*16] = 8 bf16 of G[f=32kk+8(lane>>4)+j][a=16n+(lane&15)]
// ---------------------------------------------------------------------------
__global__ __launch_bounds__(256) void k_prep(const float* __restrict__ G,
                                              unsigned char* __restrict__ gfrag) {
  const int u = blockIdx.x * 256 + threadIdx.x;   // 0..9215
  const int lane = u & 63, ng = (u >> 6) & 15, kk = u >> 10;
  const int r16 = lane & 15, g = lane >> 4;
  const int a = ng * 16 + r16;
  unsigned short h[8];
#pragma unroll
  for (int j = 0; j < 8; ++j) {
    const int f = kk * 32 + 8 * g + j;
    h[j] = (f < F_BINS) ? f2bf_rne(G[f * N_ACT + a]) : (unsigned short)0;
  }
  u32x4 w;
#pragma unroll
  for (int i = 0; i < 4; ++i)
    w[i] = (unsigned)h[2 * i] | ((unsigned)h[2 * i + 1] << 16);
  *(u32x4*)(gfrag + (size_t)u * 16) = w;
}

// ---------------------------------------------------------------------------
// GEMM+argmax only (xo^2 split out). 512 thr / 8 waves; wave (tq=wv&3,
// ah=wv>>2) owns t in [t0+64tq, +64) x actions [128ah, +128).
// A: float4 loads (lane r16 -> 4 consecutive t), depth-2 slots; fragment
// position r16 holds t = t0' + 4*r16 + tau, D-row r -> t = t0' + 4r + tau.
// B: all 144KB staged to LDS once; K-loop has zero barriers.
// ---------------------------------------------------------------------------
__global__ __launch_bounds__(NTHR, 2) void k_gemm(
    const float* __restrict__ xs, const unsigned char* __restrict__ gfrag,
    unsigned* __restrict__ maskp) {
  const int tid = threadIdx.x, lane = tid & 63, wv = tid >> 6;
  const int tq = wv & 3, ah = wv >> 2;
  const int g = lane >> 4, r16 = lane & 15;
  const int t0 = blockIdx.x * TM;
  const int tcol = t0 + 64 * tq + 4 * r16;

  __shared__ __align__(16) unsigned char Bb[147456];  // all 9 B kk-slices
  __shared__ u64 mbuf[2][TM];
  __shared__ unsigned lmask[8];
  if (tid < 8) lmask[tid] = 0u;

  // ---- stage ALL of B first (oldest in vm queue): 144 x 1KB chunks ----
#pragma unroll
  for (int i = 0; i < 18; ++i) {
    const int c = 18 * wv + i;
    const unsigned char* src = gfrag + (size_t)c * 1024 + (size_t)lane * 16;
    unsigned char* dst = &Bb[c * 1024];
    __builtin_amdgcn_global_load_lds(
        (const __attribute__((address_space(1))) unsigned*)src,
        (__attribute__((address_space(3))) unsigned*)dst, 16, 0, 0);
  }

  // A: 8 float4 into slot s (j = f-offset); one instr = 1KB/wave, 256B lines
#define LOAD_A4(s, kkv)                                                       \
  {                                                                           \
    _Pragma("unroll") for (int j = 0; j < 8; ++j) {                           \
      int f = 32 * (kkv) + 8 * g + j;                                         \
      if ((kkv) == 8) f = f > 256 ? 256 : f; /* Gfrag zero rows cover pad */  \
      va[s][j] = *(const float4*)(xs + (size_t)f * T_STEPS + tcol);           \
    }                                                                         \
  }

  float4 va[2][8];
  LOAD_A4(0, 0)
  LOAD_A4(1, 1)
  asm volatile("s_waitcnt vmcnt(16)" ::: "memory");  // B staged; A in flight
  __builtin_amdgcn_s_barrier();                      // all waves' B visible

  f32x4 acc[4][8];   // [tau][n]: row r -> t = t0'+4r+tau, a = 128ah+16n+r16
#pragma unroll
  for (int tau = 0; tau < 4; ++tau)
#pragma unroll
    for (int n = 0; n < 8; ++n) acc[tau][n] = (f32x4){0.f, 0.f, 0.f, 0.f};

#define MKAF(c) __builtin_bit_cast(s16x8, (u32x4){                            \
      pack_bf(va[s][1].c, va[s][0].c), pack_bf(va[s][3].c, va[s][2].c),       \
      pack_bf(va[s][5].c, va[s][4].c), pack_bf(va[s][7].c, va[s][6].c)})

#pragma unroll
  for (int kk = 0; kk < 9; ++kk) {
    const int s = kk & 1;
    // compiler inserts counted vmcnt for va[s] (8 younger loads may fly)
    s16x8 af[4];
    af[0] = MKAF(x); af[1] = MKAF(y); af[2] = MKAF(z); af[3] = MKAF(w);
    if (kk + 2 <= 8) LOAD_A4(s, kk + 2)
    const unsigned char* bp = &Bb[((kk * 16 + 8 * ah) * 64 + lane) * 16];
#pragma unroll
    for (int n = 0; n < 8; ++n) {
      const s16x8 bfr = *(const s16x8*)(bp + n * 1024);
#pragma unroll
      for (int tau = 0; tau < 4; ++tau)
        acc[tau][n] = __builtin_amdgcn_mfma_f32_16x16x32_bf16(
            af[tau], bfr, acc[tau][n], 0, 0, 0);
    }
  }
#undef LOAD_A4
#undef MKAF

  // ---- argmax per row r=4g+q, t = t0 + 64tq + 4r + tau, over 128 actions --
#pragma unroll
  for (int tau = 0; tau < 4; ++tau) {
#pragma unroll
    for (int q = 0; q < 4; ++q) {
      float bv = acc[tau][0][q];
      int   bc = 128 * ah + r16;
#pragma unroll
      for (int n = 1; n < 8; ++n) {
        const int c = 128 * ah + 16 * n + r16;
        if (acc[tau][n][q] > bv) { bv = acc[tau][n][q]; bc = c; }
      }
      u64 key = ((u64)mono(bv) << 32) | (unsigned)(~bc);
#pragma unroll
      for (int m = 1; m <= 8; m <<= 1) {   // reduce over r16 (lane bits 0..3)
        const u64 ok = __shfl_xor(key, m, 64);
        if (ok > key) key = ok;
      }
      if (r16 == 0)
        mbuf[ah][64 * tq + 4 * (4 * g + q) + tau] = key;
    }
  }
  __syncthreads();
  if (tid < TM) {
    const u64 k0 = mbuf[0][tid], k1 = mbuf[1][tid];
    const u64 k = k0 >= k1 ? k0 : k1;   // tie -> lower action (ah=0, ~bc max)
    const unsigned bc = ~(unsigned)(k & 0xFFFFFFFFull);
    atomicOr(&lmask[bc >> 5], 1u << (bc & 31));
  }
  __syncthreads();
  if (tid < 8) maskp[blockIdx.x * 8 + tid] = lmask[tid];
}

// ---------------------------------------------------------------------------
// Pure streaming sum of x_out^2 (ablation reference: should run ~11 us).
// ---------------------------------------------------------------------------
__global__ __launch_bounds__(256) void k_xo(const float4* __restrict__ xo4,
                                            double* __restrict__ Sb) {
  double ds = 0.0;
  for (int i = blockIdx.x * blockDim.x + threadIdx.x; i < XO_N4;
       i += gridDim.x * blockDim.x) {
    const float4 v = xo4[i];
    ds += (double)fmaf(v.x, v.x, v.y * v.y) + (double)fmaf(v.z, v.z, v.w * v.w);
  }
#pragma unroll
  for (int off = 32; off; off >>= 1) ds += __shfl_down(ds, off);
  __shared__ double sd[4];
  if ((threadIdx.x & 63) == 0) sd[threadIdx.x >> 6] = ds;
  __syncthreads();
  if (threadIdx.x == 0) atomicAdd(Sb, sd[0] + sd[1] + sd[2] + sd[3]);
}

// ---------------------------------------------------------------------------
// OR-reduce per-block masks, then correction for selected columns t = a:
//   Sc += sum_f (G*xs)^2 - 2*(G*xs)*xo
// ---------------------------------------------------------------------------
__global__ __launch_bounds__(256) void k_corr(
    const float* __restrict__ xs, const float* __restrict__ xo,
    const float* __restrict__ G, const unsigned* __restrict__ maskp,
    double* __restrict__ Sc) {
  __shared__ unsigned m8[8];
  const int tid = threadIdx.x;
  if (tid < 8) m8[tid] = 0u;
  __syncthreads();
  unsigned m = 0;
  for (int b = tid >> 3; b < NBLK_G; b += 32) m |= maskp[b * 8 + (tid & 7)];
  atomicOr(&m8[tid & 7], m);
  __syncthreads();
  const int f = blockIdx.x, a = tid;
  const bool sel = (m8[a >> 5] >> (a & 31)) & 1u;
  const float gv  = G[f * N_ACT + a];
  const float xsv = xs[(size_t)f * T_STEPS + a];
  const float xov = xo[(size_t)f * T_STEPS + a];
  const float gx  = gv * xsv;
  double acc = sel ? (double)(gx * (gx - 2.f * xov)) : 0.0;
#pragma unroll
  for (int off = 32; off; off >>= 1) acc += __shfl_down(acc, off);
  __shared__ double sdc[4];
  if ((tid & 63) == 0) sdc[tid >> 6] = acc;
  __syncthreads();
  if (tid == 0) atomicAdd(Sc, sdc[0] + sdc[1] + sdc[2] + sdc[3]);
}

__global__ void k_final(const double* __restrict__ Sb,
                        const double* __restrict__ Sc,
                        float* __restrict__ out) {
  out[0] = (float)((Sb[0] + Sc[0]) / ((double)F_BINS * (double)T_STEPS));
}

extern "C" void kernel_launch(void* const* d_in, const int* in_sizes, int n_in,
                              void* d_out, int out_size, void* d_ws, size_t ws_size,
                              hipStream_t stream) {
  const float* x_out    = (const float*)d_in[0];
  const float* x_source = (const float*)d_in[1];
  // d_in[2] (x_clean) is dead: argmin_a(clean_sum - proj) == argmax_a proj
  const float* G        = (const float*)d_in[3];

  char* ws = (char*)d_ws;
  double*        Sc    = (double*)(ws + WS_SC);
  double*        Sb    = (double*)(ws + WS_SB);
  unsigned*      maskp = (unsigned*)(ws + WS_MASK);
  unsigned char* gfrag = (unsigned char*)(ws + WS_GFRAG);

  hipMemsetAsync(d_ws, 0, 64, stream);   // Sc, Sb
  k_prep <<<36, 256, 0, stream>>>(G, gfrag);
  k_gemm <<<NBLK_G, NTHR, 0, stream>>>(x_source, gfrag, maskp);
  k_xo   <<<2048, 256, 0, stream>>>((const float4*)x_out, Sb);
  k_corr <<<F_BINS, 256, 0, stream>>>(x_source, x_out, G, maskp, Sc);
  k_final<<<1, 1, 0, stream>>>(Sb, Sc, (float*)d_out);
}

// Round 12
// 46.155 us; speedup vs baseline: 1.5916x; 1.5916x over previous
//
#include <hip/hip_runtime.h>

#define F_BINS  257
#define T_STEPS 65536
#define N_ACT   256
#define TM      256           // t-columns per k_gemm block
#define NBLK_G  256           // T_STEPS / TM  (1 block per CU, single pass)
#define NTHR    512           // 8 waves
#define XO_N4   4210688       // total float4 in x_out (257*65536/4)
#define XO_BLKS 2048
#define XO_S    524288        // XO_BLKS*256 threads

typedef float f32x4 __attribute__((ext_vector_type(4)));
typedef short s16x8 __attribute__((ext_vector_type(8)));
typedef unsigned u32x4 __attribute__((ext_vector_type(4)));
typedef unsigned long long u64;

// ws layout (everything below is FULLY WRITTEN every call - no memset needed):
//   [1024]   double partial[XO_BLKS]   (per-block xo^2 sums)
//   [20480]  double corrp[257]         (per-f correction sums)
//   [24576]  unsigned maskp[NBLK_G*8]
//   [65536]  uchar Gfrag[147456]       (B frags, MFMA order: [kk][n][lane][16B])
#define WS_PART  1024
#define WS_CORR  20480
#define WS_MASK  24576
#define WS_GFRAG 65536

__device__ __forceinline__ unsigned short f2bf_rne(float x) {
  unsigned u = __builtin_bit_cast(unsigned, x);
  return (unsigned short)((u + 0x7FFFu + ((u >> 16) & 1u)) >> 16);
}
// bf16(hi)<<16 | bf16(lo) by truncation: one v_perm_b32
__device__ __forceinline__ unsigned pack_bf(float hi, float lo) {
  return __builtin_amdgcn_perm(__builtin_bit_cast(unsigned, hi),
                               __builtin_bit_cast(unsigned, lo), 0x07060302u);
}
// monotonic float->u32 (order-preserving, finite inputs)
__device__ __forceinline__ unsigned mono(float v) {
  unsigned u = __builtin_bit_cast(unsigned, v);
  return u ^ (unsigned)(((int)u >> 31) | (int)0x80000000);
}

// ---------------------------------------------------------------------------
// B fragments in MFMA order:
// Gfrag[((kk*16+n)*64+lane)*16] = 8 bf16 of G[f=32kk+8(lane>>4)+j][a=16n+(lane&15)]
// ---------------------------------------------------------------------------
__global__ __launch_bounds__(256) void k_prep(const float* __restrict__ G,
                                              unsigned char* __restrict__ gfrag) {
  const int u = blockIdx.x * 256 + threadIdx.x;   // 0..9215
  const int lane = u & 63, ng = (u >> 6) & 15, kk = u >> 10;
  const int r16 = lane & 15, g = lane >> 4;
  const int a = ng * 16 + r16;
  unsigned short h[8];
#pragma unroll
  for (int j = 0; j < 8; ++j) {
    const int f = kk * 32 + 8 * g + j;
    h[j] = (f < F_BINS) ? f2bf_rne(G[f * N_ACT + a]) : (unsigned short)0;
  }
  u32x4 w;
#pragma unroll
  for (int i = 0; i < 4; ++i)
    w[i] = (unsigned)h[2 * i] | ((unsigned)h[2 * i + 1] << 16);
  *(u32x4*)(gfrag + (size_t)u * 16) = w;
}

// ---------------------------------------------------------------------------
// GEMM+argmax (unchanged from round 11 - it passed and is now sub-44us).
// ---------------------------------------------------------------------------
__global__ __launch_bounds__(NTHR, 2) void k_gemm(
    const float* __restrict__ xs, const unsigned char* __restrict__ gfrag,
    unsigned* __restrict__ maskp) {
  const int tid = threadIdx.x, lane = tid & 63, wv = tid >> 6;
  const int tq = wv & 3, ah = wv >> 2;
  const int g = lane >> 4, r16 = lane & 15;
  const int t0 = blockIdx.x * TM;
  const int tcol = t0 + 64 * tq + 4 * r16;

  __shared__ __align__(16) unsigned char Bb[147456];  // all 9 B kk-slices
  __shared__ u64 mbuf[2][TM];
  __shared__ unsigned lmask[8];
  if (tid < 8) lmask[tid] = 0u;

  // ---- stage ALL of B first (oldest in vm queue): 144 x 1KB chunks ----
#pragma unroll
  for (int i = 0; i < 18; ++i) {
    const int c = 18 * wv + i;
    const unsigned char* src = gfrag + (size_t)c * 1024 + (size_t)lane * 16;
    unsigned char* dst = &Bb[c * 1024];
    __builtin_amdgcn_global_load_lds(
        (const __attribute__((address_space(1))) unsigned*)src,
        (__attribute__((address_space(3))) unsigned*)dst, 16, 0, 0);
  }

  // A: 8 float4 into slot s (j = f-offset); one instr = 1KB/wave, 256B lines
#define LOAD_A4(s, kkv)                                                       \
  {                                                                           \
    _Pragma("unroll") for (int j = 0; j < 8; ++j) {                           \
      int f = 32 * (kkv) + 8 * g + j;                                         \
      if ((kkv) == 8) f = f > 256 ? 256 : f; /* Gfrag zero rows cover pad */  \
      va[s][j] = *(const float4*)(xs + (size_t)f * T_STEPS + tcol);           \
    }                                                                         \
  }

  float4 va[2][8];
  LOAD_A4(0, 0)
  LOAD_A4(1, 1)
  asm volatile("s_waitcnt vmcnt(16)" ::: "memory");  // B staged; A in flight
  __builtin_amdgcn_s_barrier();                      // all waves' B visible

  f32x4 acc[4][8];   // [tau][n]: row r -> t = t0'+4r+tau, a = 128ah+16n+r16
#pragma unroll
  for (int tau = 0; tau < 4; ++tau)
#pragma unroll
    for (int n = 0; n < 8; ++n) acc[tau][n] = (f32x4){0.f, 0.f, 0.f, 0.f};

#define MKAF(c) __builtin_bit_cast(s16x8, (u32x4){                            \
      pack_bf(va[s][1].c, va[s][0].c), pack_bf(va[s][3].c, va[s][2].c),       \
      pack_bf(va[s][5].c, va[s][4].c), pack_bf(va[s][7].c, va[s][6].c)})

#pragma unroll
  for (int kk = 0; kk < 9; ++kk) {
    const int s = kk & 1;
    s16x8 af[4];
    af[0] = MKAF(x); af[1] = MKAF(y); af[2] = MKAF(z); af[3] = MKAF(w);
    if (kk + 2 <= 8) LOAD_A4(s, kk + 2)
    const unsigned char* bp = &Bb[((kk * 16 + 8 * ah) * 64 + lane) * 16];
#pragma unroll
    for (int n = 0; n < 8; ++n) {
      const s16x8 bfr = *(const s16x8*)(bp + n * 1024);
#pragma unroll
      for (int tau = 0; tau < 4; ++tau)
        acc[tau][n] = __builtin_amdgcn_mfma_f32_16x16x32_bf16(
            af[tau], bfr, acc[tau][n], 0, 0, 0);
    }
  }
#undef LOAD_A4
#undef MKAF

  // ---- argmax per row r=4g+q, t = t0 + 64tq + 4r + tau, over 128 actions --
#pragma unroll
  for (int tau = 0; tau < 4; ++tau) {
#pragma unroll
    for (int q = 0; q < 4; ++q) {
      float bv = acc[tau][0][q];
      int   bc = 128 * ah + r16;
#pragma unroll
      for (int n = 1; n < 8; ++n) {
        const int c = 128 * ah + 16 * n + r16;
        if (acc[tau][n][q] > bv) { bv = acc[tau][n][q]; bc = c; }
      }
      u64 key = ((u64)mono(bv) << 32) | (unsigned)(~bc);
#pragma unroll
      for (int m = 1; m <= 8; m <<= 1) {   // reduce over r16 (lane bits 0..3)
        const u64 ok = __shfl_xor(key, m, 64);
        if (ok > key) key = ok;
      }
      if (r16 == 0)
        mbuf[ah][64 * tq + 4 * (4 * g + q) + tau] = key;
    }
  }
  __syncthreads();
  if (tid < TM) {
    const u64 k0 = mbuf[0][tid], k1 = mbuf[1][tid];
    const u64 k = k0 >= k1 ? k0 : k1;   // tie -> lower action (ah=0, ~bc max)
    const unsigned bc = ~(unsigned)(k & 0xFFFFFFFFull);
    atomicOr(&lmask[bc >> 5], 1u << (bc & 31));
  }
  __syncthreads();
  if (tid < 8) maskp[blockIdx.x * 8 + tid] = lmask[tid];
}

// ---------------------------------------------------------------------------
// Streaming sum of x_out^2: 8 independent float4 loads/thread (8KB/wave in
// flight), per-block partial write, ZERO atomics.
// ---------------------------------------------------------------------------
__global__ __launch_bounds__(256) void k_xo(const float4* __restrict__ xo4,
                                            double* __restrict__ partial) {
  const int tid = threadIdx.x;
  const size_t base = (size_t)blockIdx.x * 256 + tid;
  float4 v[8];
#pragma unroll
  for (int j = 0; j < 8; ++j) v[j] = xo4[base + (size_t)j * XO_S];
  double ds = 0.0;
#pragma unroll
  for (int j = 0; j < 8; ++j)
    ds += (double)fmaf(v[j].x, v[j].x, v[j].y * v[j].y) +
          (double)fmaf(v[j].z, v[j].z, v[j].w * v[j].w);
  if (base < XO_N4 - 8 * XO_S) {   // tail: 16384 float4
    const float4 w = xo4[8 * XO_S + base];
    ds += (double)fmaf(w.x, w.x, w.y * w.y) + (double)fmaf(w.z, w.z, w.w * w.w);
  }
#pragma unroll
  for (int off = 32; off; off >>= 1) ds += __shfl_down(ds, off);
  __shared__ double sd[4];
  if ((tid & 63) == 0) sd[tid >> 6] = ds;
  __syncthreads();
  if (tid == 0) partial[blockIdx.x] = sd[0] + sd[1] + sd[2] + sd[3];
}

// ---------------------------------------------------------------------------
// OR-reduce per-block masks, then correction for selected columns t = a:
//   corrp[f] = sum_a sel[a] * ((G*xs)^2 - 2*(G*xs)*xo)  -- no atomics
// ---------------------------------------------------------------------------
__global__ __launch_bounds__(256) void k_corr(
    const float* __restrict__ xs, const float* __restrict__ xo,
    const float* __restrict__ G, const unsigned* __restrict__ maskp,
    double* __restrict__ corrp) {
  __shared__ unsigned m8[8];
  const int tid = threadIdx.x;
  if (tid < 8) m8[tid] = 0u;
  __syncthreads();
  unsigned m = 0;
  for (int b = tid >> 3; b < NBLK_G; b += 32) m |= maskp[b * 8 + (tid & 7)];
  atomicOr(&m8[tid & 7], m);
  __syncthreads();
  const int f = blockIdx.x, a = tid;
  const bool sel = (m8[a >> 5] >> (a & 31)) & 1u;
  const float gv  = G[f * N_ACT + a];
  const float xsv = xs[(size_t)f * T_STEPS + a];
  const float xov = xo[(size_t)f * T_STEPS + a];
  const float gx  = gv * xsv;
  double acc = sel ? (double)(gx * (gx - 2.f * xov)) : 0.0;
#pragma unroll
  for (int off = 32; off; off >>= 1) acc += __shfl_down(acc, off);
  __shared__ double sdc[4];
  if ((tid & 63) == 0) sdc[tid >> 6] = acc;
  __syncthreads();
  if (tid == 0) corrp[f] = sdc[0] + sdc[1] + sdc[2] + sdc[3];
}

// ---------------------------------------------------------------------------
// Final reduction: partial[2048] + corrp[257] -> loss
// ---------------------------------------------------------------------------
__global__ __launch_bounds__(256) void k_final(const double* __restrict__ partial,
                                               const double* __restrict__ corrp,
                                               float* __restrict__ out) {
  const int tid = threadIdx.x;
  double s = 0.0;
#pragma unroll
  for (int i = 0; i < 8; ++i) s += partial[tid + 256 * i];
  s += corrp[tid];
  if (tid == 0) s += corrp[256];
#pragma unroll
  for (int off = 32; off; off >>= 1) s += __shfl_down(s, off);
  __shared__ double sd[4];
  if ((tid & 63) == 0) sd[tid >> 6] = s;
  __syncthreads();
  if (tid == 0)
    out[0] = (float)((sd[0] + sd[1] + sd[2] + sd[3]) /
                     ((double)F_BINS * (double)T_STEPS));
}

extern "C" void kernel_launch(void* const* d_in, const int* in_sizes, int n_in,
                              void* d_out, int out_size, void* d_ws, size_t ws_size,
                              hipStream_t stream) {
  const float* x_out    = (const float*)d_in[0];
  const float* x_source = (const float*)d_in[1];
  // d_in[2] (x_clean) is dead: argmin_a(clean_sum - proj) == argmax_a proj
  const float* G        = (const float*)d_in[3];

  char* ws = (char*)d_ws;
  double*        partial = (double*)(ws + WS_PART);
  double*        corrp   = (double*)(ws + WS_CORR);
  unsigned*      maskp   = (unsigned*)(ws + WS_MASK);
  unsigned char* gfrag   = (unsigned char*)(ws + WS_GFRAG);

  // no memset: partial, corrp, maskp, gfrag are fully written every call
  k_prep <<<36, 256, 0, stream>>>(G, gfrag);
  k_gemm <<<NBLK_G, NTHR, 0, stream>>>(x_source, gfrag, maskp);
  k_xo   <<<XO_BLKS, 256, 0, stream>>>((const float4*)x_out, partial);
  k_corr <<<F_BINS, 256, 0, stream>>>(x_source, x_out, G, maskp, corrp);
  k_final<<<1, 256, 0, stream>>>(partial, corrp, (float*)d_out);
}